// Round 1
// baseline (120.045 us; speedup 1.0000x reference)
//
#include <hip/hip_runtime.h>
#include <hip/hip_bf16.h>

// Shift SSM == causal 64-tap FIR per channel + skip (D folded into tap 0).
// R5: same MFMA formulation as R4 (3x mfma_f32_16x16x32_bf16 per 16x16 tile,
// Toeplitz windows from a swizzled bf16 LDS row), plus:
//  - v_cvt_pk_bf16_f32 for all fp32->bf16 packing (RNE, bit-identical to the
//    old f2bf; 2 VALU per float4 instead of ~16)
//  - hoisted staging loads (16KB/block in flight)
//  - output-row permutation perm(m)=((m&3)<<2)|(m>>2) so every
//    global_store_dword is one contiguous 256B wave transaction
//  - 4-way ILP in the tap dot product

#define D_MODEL 512
#define D_STATE 64
#define BATCH   8
#define SEQ_L   4096
#define NT      256

typedef short           s16x8 __attribute__((ext_vector_type(8)));
typedef unsigned short  u16;
typedef unsigned int    u32;
typedef u32             u32x2 __attribute__((ext_vector_type(2)));
typedef u32             u32x4 __attribute__((ext_vector_type(4)));
typedef float           f32x4 __attribute__((ext_vector_type(4)));

// XOR swizzle on 16B LDS chunks (applied at write AND read): spreads the
// stride-32B a-frag reads / stride-64B staging writes across bank groups.
__device__ __forceinline__ int SW(int g) { return g ^ ((g >> 3) & 7); }

// RNE pack of two f32 into one u32 of 2x bf16 (lo = first arg).
__device__ __forceinline__ u32 cvt_pk(float lo, float hi) {
    u32 r;
    asm("v_cvt_pk_bf16_f32 %0, %1, %2" : "=v"(r) : "v"(lo), "v"(hi));
    return r;
}

__global__ void __launch_bounds__(NT)
shift_mfma(const float* __restrict__ u, const float* __restrict__ B,
           const float* __restrict__ C, const float* __restrict__ D,
           float* __restrict__ y) {
    const int row = blockIdx.x;              // b*512 + h
    const int h   = row & (D_MODEL - 1);
    const float* __restrict__ urow = u + (size_t)row * SEQ_L;
    float* __restrict__ yrow       = y + (size_t)row * SEQ_L;

    // bf16 row with 64-elem front halo + zero tail; 536 chunks of 8 elems.
    __shared__ u16   ub[536 * 8];
    __shared__ float Bs[64];
    __shared__ float Cs[128];                // zero-padded
    __shared__ float Kf[64];

    const int t = threadIdx.x;

    // ---- stage B, C rows ----
    if (t < 16) {
        ((float4*)Bs)[t] = ((const float4*)(B + h * D_STATE))[t];
    } else if (t < 48) {
        const int j = t - 16;
        ((float4*)Cs)[j] = (j < 16) ? ((const float4*)(C + h * D_STATE))[j]
                                    : make_float4(0.f, 0.f, 0.f, 0.f);
    }

    // ---- stage u row -> bf16 LDS: hoisted float4 loads, cvt_pk, swizzled
    //      8B writes ----
    const float4 v0 = *(const float4*)(urow + 4 * t + 0);
    const float4 v1 = *(const float4*)(urow + 4 * t + 1024);
    const float4 v2 = *(const float4*)(urow + 4 * t + 2048);
    const float4 v3 = *(const float4*)(urow + 4 * t + 3072);
    {
        const float4 vv[4] = {v0, v1, v2, v3};
        #pragma unroll
        for (int j = 0; j < 4; ++j) {
            u32x2 pk = { cvt_pk(vv[j].x, vv[j].y), cvt_pk(vv[j].z, vv[j].w) };
            const int byte = 128 + 8 * t + 2048 * j;        // halo offset 128 B
            const int sb   = (SW(byte >> 4) << 4) | (byte & 8);
            *(u32x2*)((char*)ub + sb) = pk;
        }
    }
    // halo zeros: front chunks 0..7 (elems L<64), tail chunks 520..531
    if (t < 8) {
        u32x4 z = {0, 0, 0, 0};
        *(u32x4*)((char*)ub + (SW(t) << 4)) = z;
    } else if (t < 20) {
        u32x4 z = {0, 0, 0, 0};
        const int g = 520 + (t - 8);
        *(u32x4*)((char*)ub + (SW(g) << 4)) = z;
    }
    __syncthreads();

    // ---- taps: K[k] = sum_j B[j] C[k+j]  (+D at k=0), 4-way ILP ----
    if (t < D_STATE) {
        float s0 = 0.f, s1 = 0.f, s2 = 0.f, s3 = 0.f;
        #pragma unroll
        for (int j = 0; j < D_STATE; j += 4) {
            s0 = fmaf(Bs[j + 0], Cs[t + j + 0], s0);
            s1 = fmaf(Bs[j + 1], Cs[t + j + 1], s1);
            s2 = fmaf(Bs[j + 2], Cs[t + j + 2], s2);
            s3 = fmaf(Bs[j + 3], Cs[t + j + 3], s3);
        }
        float s = (s0 + s1) + (s2 + s3);
        if (t == 0) s += D[h];
        Kf[t] = s;
    }
    __syncthreads();

    // ---- b-frags: T[p][i] = K[64+i-p], p = 32c + 8q + j, i = lane&15 ----
    const int l  = t & 63;
    const int n  = l & 15;                   // output col within tile
    const int q  = l >> 4;                   // k-quad
    const int pm = ((n & 3) << 2) | (n >> 2); // output-row permutation
    u32x4 bfr[3];
    #pragma unroll
    for (int c = 0; c < 3; ++c) {
        float tv[8];
        #pragma unroll
        for (int j = 0; j < 8; ++j) {
            const int p = 32 * c + 8 * q + j;
            const int k = 64 + n - p;
            tv[j] = (k >= 0 && k < D_STATE) ? Kf[k] : 0.f;
        }
        #pragma unroll
        for (int w = 0; w < 4; ++w) bfr[c][w] = cvt_pk(tv[2 * w], tv[2 * w + 1]);
    }

    // ---- 4 tiles (of 256 outputs) per wave ----
    // A-row m' = n supplies window perm(n); D row m=4q+r is output window
    // perm(m)=4r+q, so store addr = base + 64r + (16q+n) = base + 64r + lane:
    // each store instruction is one contiguous 256B wave transaction.
    const int wbase = 1024 * (t >> 6);
    #pragma unroll
    for (int tt = 0; tt < 4; ++tt) {
        const int base = wbase + 256 * tt;
        f32x4 acc = {0.f, 0.f, 0.f, 0.f};
        #pragma unroll
        for (int c = 0; c < 3; ++c) {
            // lane reads 8 consecutive bf16 at L = base + 16*pm + 32c + 8q
            // (window start -64 cancels halo +64)
            const int L  = base + 16 * pm + 32 * c + 8 * q;
            const int sb = SW(L >> 3) << 4;
            const s16x8 a = *(const s16x8*)((const char*)ub + sb);
            acc = __builtin_amdgcn_mfma_f32_16x16x32_bf16(
                      a, __builtin_bit_cast(s16x8, bfr[c]), acc, 0, 0, 0);
        }
        #pragma unroll
        for (int r = 0; r < 4; ++r)
            yrow[base + 64 * r + 16 * q + n] = acc[r];
    }
}

extern "C" void kernel_launch(void* const* d_in, const int* in_sizes, int n_in,
                              void* d_out, int out_size, void* d_ws, size_t ws_size,
                              hipStream_t stream) {
    const float* u = (const float*)d_in[0];   // (8, 512, 4096)
    const float* B = (const float*)d_in[1];   // (512, 64)
    const float* C = (const float*)d_in[2];   // (1, 512, 64)
    const float* D = (const float*)d_in[3];   // (512,)
    float* y = (float*)d_out;                 // (8, 512, 4096)

    shift_mfma<<<dim3(BATCH * D_MODEL), dim3(NT), 0, stream>>>(u, B, C, D, y);
}

// Round 2
// 119.904 us; speedup vs baseline: 1.0012x; 1.0012x over previous
//
#include <hip/hip_runtime.h>

// Shift SSM == causal 64-tap FIR per channel + skip (D folded into tap 0).
// R6: 2-row blocks + operand-swapped MFMA.
//  - Block handles rows (bid, bid+2048): same h -> taps, B/C staging, barrier
//    cost and A-fragment build amortize over 2 rows; 8 float4 loads in
//    flight per thread (2x MLP).
//  - Operand swap: A = banded tap matrix K[m+64-p] (16x96), B = Toeplitz
//    u-windows u[base+16i+p-64] (96x16). D layout (col=lane&15, row=4q+r)
//    then makes each thread's 4 outputs CONSECUTIVE: one dwordx4 store per
//    16x16 tile, 1KB contiguous per wave store instruction.
//  - Swizzled bf16 LDS row per R4/R5 (SW on 16B chunks, write and read).

#define D_MODEL 512
#define D_STATE 64
#define BATCH   8
#define SEQ_L   4096
#define NT      256
#define NBLK    2048          // grid: 2 rows per block
#define CH      536           // 16B chunks per row buffer (8 halo + 512 + 12 tail + pad)

typedef short           s16x8 __attribute__((ext_vector_type(8)));
typedef unsigned short  u16;
typedef unsigned int    u32;
typedef u32             u32x2 __attribute__((ext_vector_type(2)));
typedef u32             u32x4 __attribute__((ext_vector_type(4)));
typedef float           f32x4 __attribute__((ext_vector_type(4)));

// XOR swizzle on 16B LDS chunks (applied at write AND read).
__device__ __forceinline__ int SW(int g) { return g ^ ((g >> 3) & 7); }

// RNE pack of two f32 into one u32 of 2x bf16 (lo = first arg).
__device__ __forceinline__ u32 cvt_pk(float lo, float hi) {
    u32 r;
    asm("v_cvt_pk_bf16_f32 %0, %1, %2" : "=v"(r) : "v"(lo), "v"(hi));
    return r;
}

__global__ void __launch_bounds__(NT)
shift_mfma(const float* __restrict__ u, const float* __restrict__ B,
           const float* __restrict__ C, const float* __restrict__ D,
           float* __restrict__ y) {
    const int bid = blockIdx.x;
    const int h   = bid & (D_MODEL - 1);          // rows bid and bid+2048 share h
    const float* __restrict__ ur0 = u + (size_t)bid * SEQ_L;
    const float* __restrict__ ur1 = u + (size_t)(bid + NBLK) * SEQ_L;
    float* __restrict__ yr0       = y + (size_t)bid * SEQ_L;
    float* __restrict__ yr1       = y + (size_t)(bid + NBLK) * SEQ_L;

    __shared__ u16   ub[2 * CH * 8];
    __shared__ float Bs[64];
    __shared__ float Cs[128];                     // zero-padded
    __shared__ float Kf[64];

    const int t = threadIdx.x;

    // ---- issue all 8 staging loads up front (2x MLP) ----
    const float4 v0 = *(const float4*)(ur0 + 4 * t + 0);
    const float4 v1 = *(const float4*)(ur0 + 4 * t + 1024);
    const float4 v2 = *(const float4*)(ur0 + 4 * t + 2048);
    const float4 v3 = *(const float4*)(ur0 + 4 * t + 3072);
    const float4 w0 = *(const float4*)(ur1 + 4 * t + 0);
    const float4 w1 = *(const float4*)(ur1 + 4 * t + 1024);
    const float4 w2 = *(const float4*)(ur1 + 4 * t + 2048);
    const float4 w3 = *(const float4*)(ur1 + 4 * t + 3072);

    // ---- stage B, C rows ----
    if (t < 16) {
        ((float4*)Bs)[t] = ((const float4*)(B + h * D_STATE))[t];
    } else if (t < 48) {
        const int j = t - 16;
        ((float4*)Cs)[j] = (j < 16) ? ((const float4*)(C + h * D_STATE))[j]
                                    : make_float4(0.f, 0.f, 0.f, 0.f);
    }

    // ---- cvt + swizzled 8B LDS writes, both rows ----
    {
        const float4 vv[8] = {v0, v1, v2, v3, w0, w1, w2, w3};
        #pragma unroll
        for (int j = 0; j < 8; ++j) {
            u32x2 pk = { cvt_pk(vv[j].x, vv[j].y), cvt_pk(vv[j].z, vv[j].w) };
            const int byte = 128 + 8 * t + 2048 * (j & 3);   // halo offset 128 B
            const int sb   = (SW(byte >> 4) << 4) | (byte & 8);
            *(u32x2*)((char*)ub + (j >> 2) * (CH * 16) + sb) = pk;
        }
    }
    // halo zeros: front chunks 0..7, tail chunks 520..531, per buffer
    {
        const u32x4 z = {0, 0, 0, 0};
        if (t < 8)
            *(u32x4*)((char*)ub + (SW(t) << 4)) = z;
        else if (t < 16)
            *(u32x4*)((char*)ub + CH * 16 + (SW(t - 8) << 4)) = z;
        else if (t < 28)
            *(u32x4*)((char*)ub + (SW(520 + t - 16) << 4)) = z;
        else if (t < 40)
            *(u32x4*)((char*)ub + CH * 16 + (SW(520 + t - 28) << 4)) = z;
    }
    __syncthreads();

    // ---- taps: K[k] = sum_j B[j] C[k+j]  (+D at k=0), 4-way ILP ----
    if (t < D_STATE) {
        float s0 = 0.f, s1 = 0.f, s2 = 0.f, s3 = 0.f;
        #pragma unroll
        for (int j = 0; j < D_STATE; j += 4) {
            s0 = fmaf(Bs[j + 0], Cs[t + j + 0], s0);
            s1 = fmaf(Bs[j + 1], Cs[t + j + 1], s1);
            s2 = fmaf(Bs[j + 2], Cs[t + j + 2], s2);
            s3 = fmaf(Bs[j + 3], Cs[t + j + 3], s3);
        }
        float s = (s0 + s1) + (s2 + s3);
        if (t == 0) s += D[h];
        Kf[t] = s;
    }
    __syncthreads();

    // ---- A-frags (taps): A[m][p] = K[m + 64 - p], m = lane&15, p = 32c+8q+j ----
    const int l = t & 63;
    const int n = l & 15;                 // A row / B col / D col
    const int q = l >> 4;                 // k-quad
    u32x4 afr[3];
    #pragma unroll
    for (int c = 0; c < 3; ++c) {
        float tv[8];
        #pragma unroll
        for (int j = 0; j < 8; ++j) {
            const int k = n + 64 - (32 * c + 8 * q + j);
            tv[j] = (k >= 0 && k < D_STATE) ? Kf[k] : 0.f;
        }
        #pragma unroll
        for (int w = 0; w < 4; ++w) afr[c][w] = cvt_pk(tv[2 * w], tv[2 * w + 1]);
    }

    // ---- compute: per row, 4 tiles of 256 outputs per wave ----
    // B[p][i] = u[base + 16i + p - 64]: lane (col i=n, kq q) reads 8
    // consecutive bf16 at LDS elem E = base + 16n + 8q + 32c (halo +64
    // cancels the -64). D: out = base + 16n + 4q + r -> one dwordx4/thread.
    const int wbase = 1024 * (t >> 6);
    #pragma unroll
    for (int rr = 0; rr < 2; ++rr) {
        const char* ubase = (const char*)ub + rr * (CH * 16);
        float* __restrict__ yr = rr ? yr1 : yr0;
        #pragma unroll
        for (int tt = 0; tt < 4; ++tt) {
            const int base = wbase + 256 * tt;
            f32x4 acc = {0.f, 0.f, 0.f, 0.f};
            #pragma unroll
            for (int c = 0; c < 3; ++c) {
                const int E  = base + 16 * n + 8 * q + 32 * c;
                const int sb = SW(E >> 3) << 4;
                const s16x8 b = *(const s16x8*)(ubase + sb);
                acc = __builtin_amdgcn_mfma_f32_16x16x32_bf16(
                          __builtin_bit_cast(s16x8, afr[c]), b, acc, 0, 0, 0);
            }
            *(f32x4*)(yr + base + 16 * n + 4 * q) = acc;
        }
    }
}

extern "C" void kernel_launch(void* const* d_in, const int* in_sizes, int n_in,
                              void* d_out, int out_size, void* d_ws, size_t ws_size,
                              hipStream_t stream) {
    const float* u = (const float*)d_in[0];   // (8, 512, 4096)
    const float* B = (const float*)d_in[1];   // (512, 64)
    const float* C = (const float*)d_in[2];   // (1, 512, 64)
    const float* D = (const float*)d_in[3];   // (512,)
    float* y = (float*)d_out;                 // (8, 512, 4096)

    shift_mfma<<<dim3(NBLK), dim3(NT), 0, stream>>>(u, B, C, D, y);
}